// Round 2
// baseline (73757.495 us; speedup 1.0000x reference)
//
#include <hip/hip_runtime.h>
#include <hip/hip_bf16.h>
#include <math.h>

// Activations: [B=2][C=16][O=8][H=256][W=256] fp32 in ws.
#define HW 65536
#define WID 256
#define CH 16
#define NOR 8
#define PLANE_C (NOR * HW)          // 524288
#define PLANE_B (CH * NOR * HW)     // 8388608
#define NELEM (2 * CH * NOR * HW)   // 16777216
#define BN_N 1048576.0f

__device__ __forceinline__ float bfv(const __hip_bfloat16 v) { return __bfloat162float(v); }

// ---- runtime input-dtype detection: flag=1 -> bf16 storage, flag=0 -> fp32 ----
// Genuine N(0,1) data read as bf16 stays |v| < ~10. fp32 storage read as bf16
// puts mantissa noise in even halfwords -> random exponents -> |v| huge/NaN
// with near-certainty over 4096 samples.
__global__ void detect_k(const void* __restrict__ x, int* __restrict__ flag) {
    __shared__ int bad;
    if (threadIdx.x == 0) bad = 0;
    __syncthreads();
    const __hip_bfloat16* p = (const __hip_bfloat16*)x;
    for (int i = threadIdx.x; i < 4096; i += 256) {
        float v = __bfloat162float(p[i]);
        if (!(fabsf(v) < 1e4f)) atomicOr(&bad, 1);  // catches huge and NaN
    }
    __syncthreads();
    if (threadIdx.x == 0) *flag = bad ? 0 : 1;
}

// convert one input buffer to canonical fp32
__global__ void cvt_k(const void* __restrict__ in, float* __restrict__ out, int n,
                      const int* __restrict__ flag) {
    int i = blockIdx.x * blockDim.x + threadIdx.x;
    if (i >= n) return;
    if (*flag)
        out[i] = __bfloat162float(((const __hip_bfloat16*)in)[i]);
    else
        out[i] = ((const float*)in)[i];
}

// Bilinear kernel rotation, replicating the JAX reference in fp32.
__device__ float rot_sample(const float* __restrict__ W, int k, float theta, int i, int j) {
    float c = 0.5f * (float)(k - 1);
    float ys = (float)i - c, xs = (float)j - c;
    float cs = cosf(theta), sn = sinf(theta);
    float sy = cs * ys - sn * xs + c;
    float sx = sn * ys + cs * xs + c;
    float fy = floorf(sy), fx = floorf(sx);
    int y0 = (int)fy, x0 = (int)fx;
    float wy = sy - fy, wx = sx - fx;
    float v00 = (y0 >= 0 && y0 < k && x0 >= 0 && x0 < k)             ? W[y0 * k + x0]           : 0.f;
    float v01 = (y0 >= 0 && y0 < k && x0 + 1 >= 0 && x0 + 1 < k)     ? W[y0 * k + x0 + 1]       : 0.f;
    float v10 = (y0 + 1 >= 0 && y0 + 1 < k && x0 >= 0 && x0 < k)     ? W[(y0 + 1) * k + x0]     : 0.f;
    float v11 = (y0 + 1 >= 0 && y0 + 1 < k && x0 + 1 >= 0 && x0 + 1 < k) ? W[(y0 + 1) * k + x0 + 1] : 0.f;
    return v00 * (1 - wy) * (1 - wx) + v01 * (1 - wy) * wx
         + v10 * wy * (1 - wx) + v11 * wy * wx;
}

__device__ __forceinline__ float theta_of(int m) {
    return (6.2831855f * (float)m) / 8.0f;
}

__device__ __forceinline__ int mirror(int i) {  // reflect (no edge repeat), size 256
    i = i < 0 ? -i : i;
    return i >= WID ? (2 * WID - 2 - i) : i;
}

// ---- rotated lift weights: Wr[o][c][ci][7][7] ----
__global__ void rot_lift_k(const float* __restrict__ w, float* __restrict__ Wr) {
    int idx = blockIdx.x * blockDim.x + threadIdx.x;
    if (idx >= 8 * 16 * 3 * 49) return;
    int ij = idx % 49;
    int t = idx / 49;
    int ci = t % 3;
    int oc = t / 3;
    int c = oc & 15, o = oc >> 4;
    Wr[idx] = rot_sample(w + (c * 3 + ci) * 49, 7, theta_of(o), ij / 7, ij % 7);
}

// ---- lift conv 7x7 reflect(3): x[b][ci][256][256] -> out[b][c][o][..] ----
__global__ void lift7_k(const float* __restrict__ x, const float* __restrict__ Wr,
                        float* __restrict__ out) {
    int tile = blockIdx.x, ty = tile >> 4, tx = tile & 15;
    int oc = blockIdx.y;
    int c = oc & 15, o = oc >> 4;
    int b = blockIdx.z;
    __shared__ float Ks[3 * 49];
    for (int i = threadIdx.x; i < 147; i += 256) Ks[i] = Wr[oc * 147 + i];
    __syncthreads();
    int lx = threadIdx.x & 15, ly = threadIdx.x >> 4;
    int y = ty * 16 + ly, xq = tx * 16 + lx;
    int xs[7], yr[7];
#pragma unroll
    for (int t = 0; t < 7; t++) { xs[t] = mirror(xq + t - 3); yr[t] = mirror(y + t - 3); }
    float acc = 0.f;
#pragma unroll
    for (int ci = 0; ci < 3; ci++) {
        const float* p = x + (b * 3 + ci) * HW;
#pragma unroll
        for (int ky = 0; ky < 7; ky++) {
            const float* row = p + yr[ky] * WID;
#pragma unroll
            for (int kx = 0; kx < 7; kx++)
                acc = fmaf(row[xs[kx]], Ks[ci * 49 + ky * 7 + kx], acc);
        }
    }
    out[(size_t)b * PLANE_B + (size_t)c * PLANE_C + o * HW + y * WID + xq] = acc;
}

// ---- rotated+orientation-shifted gconv weights: Kf[m][co][ci][o][5][5] ----
__global__ void rot_gconv_k(const float* __restrict__ w, float* __restrict__ Kf) {
    int idx = blockIdx.x * blockDim.x + threadIdx.x;
    if (idx >= 819200) return;
    int ij = idx % 25;
    int t = idx / 25;
    int o = t & 7; t >>= 3;
    int ci = t & 15; t >>= 4;
    int co = t & 15;
    int m = t >> 4;
    int oo = (o - m + 8) & 7;
    Kf[idx] = rot_sample(w + ((co * 16 + ci) * 8 + oo) * 25, 5, theta_of(m), ij / 5, ij % 5);
}

// ---- gconv 5x5 reflect(2): in[b][ci][o][..] -> out[b][co][m][..] ----
__global__ void gconv5_k(const float* __restrict__ in, const float* __restrict__ Kf,
                         float* __restrict__ out) {
    int tile = blockIdx.x, ty = tile >> 4, tx = tile & 15;
    int mco = blockIdx.y;
    int co = mco & 15, m = mco >> 4;
    int b = blockIdx.z;
    __shared__ float Ks[3200];
    for (int i = threadIdx.x; i < 3200; i += 256) Ks[i] = Kf[mco * 3200 + i];
    __syncthreads();
    int lx = threadIdx.x & 15, ly = threadIdx.x >> 4;
    int y = ty * 16 + ly, xq = tx * 16 + lx;
    int xs[5], yr[5];
#pragma unroll
    for (int t = 0; t < 5; t++) { xs[t] = mirror(xq + t - 2); yr[t] = mirror(y + t - 2); }
    float acc = 0.f;
    const float* inb = in + (size_t)b * PLANE_B;
    int kidx = 0;
    for (int ci = 0; ci < 16; ci++) {
#pragma unroll
        for (int o = 0; o < 8; o++) {
            const float* p = inb + (ci * 8 + o) * HW;
#pragma unroll
            for (int ky = 0; ky < 5; ky++) {
                const float* row = p + yr[ky] * WID;
#pragma unroll
                for (int kx = 0; kx < 5; kx++)
                    acc = fmaf(row[xs[kx]], Ks[kidx + ky * 5 + kx], acc);
            }
            kidx += 25;
        }
    }
    out[(size_t)b * PLANE_B + (size_t)co * PLANE_C + m * HW + y * WID + xq] = acc;
}

// ---- 1x1 gconv ----
__global__ void conv1x1_k(const float* __restrict__ in, const float* __restrict__ w4,
                          float* __restrict__ out) {
    int tile = blockIdx.x, ty = tile >> 4, tx = tile & 15;
    int m = blockIdx.y, b = blockIdx.z;
    __shared__ float Ws[2048];
    for (int i = threadIdx.x; i < 2048; i += 256) {
        int o = i & 7, rest = i >> 3;
        Ws[i] = w4[(rest << 3) + ((o - m + 8) & 7)];
    }
    __syncthreads();
    int lx = threadIdx.x & 15, ly = threadIdx.x >> 4;
    int pix = (ty * 16 + ly) * WID + tx * 16 + lx;
    float acc[16];
#pragma unroll
    for (int i = 0; i < 16; i++) acc[i] = 0.f;
    const float* inb = in + (size_t)b * PLANE_B;
    for (int ci = 0; ci < 16; ci++) {
#pragma unroll
        for (int o = 0; o < 8; o++) {
            float v = inb[(ci * 8 + o) * HW + pix];
#pragma unroll
            for (int co = 0; co < 16; co++)
                acc[co] = fmaf(v, Ws[(co * 16 + ci) * 8 + o], acc[co]);
        }
    }
#pragma unroll
    for (int co = 0; co < 16; co++)
        out[(size_t)b * PLANE_B + (size_t)co * PLANE_C + m * HW + pix] = acc[co];
}

// ---- BN batch stats ----
__global__ void zero_k(float* p, int n) {
    int i = blockIdx.x * blockDim.x + threadIdx.x;
    if (i < n) p[i] = 0.f;
}

__global__ void stats_k(const float* __restrict__ buf, float* __restrict__ stats) {
    int c = blockIdx.x;
    float s = 0.f, s2 = 0.f;
    int total = 2 * NOR * HW;
    for (int i = blockIdx.y * blockDim.x + threadIdx.x; i < total; i += gridDim.y * blockDim.x) {
        int b = i >> 19;
        int rem = i & ((1 << 19) - 1);
        float v = buf[(size_t)b * PLANE_B + (size_t)c * PLANE_C + rem];
        s += v;
        s2 += v * v;
    }
#pragma unroll
    for (int off = 32; off > 0; off >>= 1) {
        s += __shfl_down(s, off);
        s2 += __shfl_down(s2, off);
    }
    __shared__ float ls[4], ls2[4];
    int wid = threadIdx.x >> 6, lid = threadIdx.x & 63;
    if (lid == 0) { ls[wid] = s; ls2[wid] = s2; }
    __syncthreads();
    if (threadIdx.x == 0) {
        atomicAdd(&stats[c * 2], ls[0] + ls[1] + ls[2] + ls[3]);
        atomicAdd(&stats[c * 2 + 1], ls2[0] + ls2[1] + ls2[2] + ls2[3]);
    }
}

__global__ void finalize_k(const float* __restrict__ stats, const float* __restrict__ g,
                           const float* __restrict__ beta, float* __restrict__ ss) {
    int c = threadIdx.x;
    if (c >= 16) return;
    float mean = stats[c * 2] / BN_N;
    float var = stats[c * 2 + 1] / BN_N - mean * mean;
    float sc = g[c] * rsqrtf(var + 1e-5f);
    ss[c * 2] = sc;
    ss[c * 2 + 1] = beta[c] - mean * sc;
}

__global__ void bnrelu_k(float* __restrict__ buf, const float* __restrict__ ss) {
    int i = blockIdx.x * blockDim.x + threadIdx.x;
    int c = (i >> 19) & 15;
    float v = buf[i] * ss[c * 2] + ss[c * 2 + 1];
    buf[i] = v > 0.f ? v : 0.f;
}

// ---- BN+ReLU, max over orientation, final 1x1 + sigmoid; dtype-flagged write ----
__global__ void final_k(const float* __restrict__ in, const float* __restrict__ ss,
                        const float* __restrict__ fw, void* __restrict__ out,
                        const int* __restrict__ flag) {
    int i = blockIdx.x * blockDim.x + threadIdx.x;  // 131072
    int b = i >> 16, pix = i & 65535;
    float acc = 0.f;
#pragma unroll
    for (int co = 0; co < 16; co++) {
        float sc = ss[co * 2], sh = ss[co * 2 + 1];
        float mx = 0.f;
        const float* p = in + (size_t)b * PLANE_B + (size_t)co * PLANE_C + pix;
#pragma unroll
        for (int m = 0; m < 8; m++) mx = fmaxf(mx, p[m * HW] * sc + sh);
        acc = fmaf(fw[co], mx, acc);
    }
    float r = 1.f / (1.f + expf(-acc));
    if (*flag)
        ((__hip_bfloat16*)out)[i] = __float2bfloat16(r);
    else
        ((float*)out)[i] = r;
}

extern "C" void kernel_launch(void* const* d_in, const int* in_sizes, int n_in,
                              void* d_out, int out_size, void* d_ws, size_t ws_size,
                              hipStream_t stream) {
    float* ws = (float*)d_ws;
    float* bufA  = ws;
    float* bufB  = ws + NELEM;
    float* Kf    = ws + 2 * NELEM;           // 819200
    float* WrL   = Kf + 819200;              // 18816
    float* stats = WrL + 18816;              // 32
    float* ss    = stats + 32;               // 32
    int*   flag  = (int*)(ss + 32);          // 16 (padded)
    float* conv  = ss + 48;                  // converted fp32 inputs

    // converted-input layout
    float* xF  = conv;                 // 393216
    float* lwF = xF + 393216;          // 2352
    float* w1F = lwF + 2352;           // 102400
    float* w2F = w1F + 102400;
    float* w3F = w2F + 102400;
    float* w4F = w3F + 102400;         // 2048
    float* fwF = w4F + 2048;           // 16
    float* gbF = fwF + 16;             // 160 = g0,b0,g1,b1,...,g4,b4

    detect_k<<<1, 256, 0, stream>>>(d_in[0], flag);

    // convert all inputs to fp32
    {
        float* dsts[17] = {xF, lwF, w1F, w2F, w3F, w4F, fwF,
                           gbF + 0,  gbF + 16, gbF + 32, gbF + 48, gbF + 64,
                           gbF + 80, gbF + 96, gbF + 112, gbF + 128, gbF + 144};
        for (int i = 0; i < 17; i++) {
            int n = in_sizes[i];
            cvt_k<<<(n + 255) / 256, 256, 0, stream>>>(d_in[i], dsts[i], n, flag);
        }
    }

    dim3 tgrid(256, 128, 2);
    dim3 cgrid(256, 8, 2);

    // lift
    rot_lift_k<<<(18816 + 255) / 256, 256, 0, stream>>>(lwF, WrL);
    lift7_k<<<tgrid, 256, 0, stream>>>(xF, WrL, bufA);
    zero_k<<<1, 64, 0, stream>>>(stats, 32);
    stats_k<<<dim3(16, 64), 256, 0, stream>>>(bufA, stats);
    finalize_k<<<1, 64, 0, stream>>>(stats, gbF + 0, gbF + 16, ss);
    bnrelu_k<<<NELEM / 256, 256, 0, stream>>>(bufA, ss);

    // gconv 1..3
    float* wlist[3] = {w1F, w2F, w3F};
    float* src = bufA;
    float* dst = bufB;
    for (int l = 0; l < 3; l++) {
        rot_gconv_k<<<(819200 + 255) / 256, 256, 0, stream>>>(wlist[l], Kf);
        gconv5_k<<<tgrid, 256, 0, stream>>>(src, Kf, dst);
        zero_k<<<1, 64, 0, stream>>>(stats, 32);
        stats_k<<<dim3(16, 64), 256, 0, stream>>>(dst, stats);
        finalize_k<<<1, 64, 0, stream>>>(stats, gbF + 32 * (l + 1), gbF + 32 * (l + 1) + 16, ss);
        bnrelu_k<<<NELEM / 256, 256, 0, stream>>>(dst, ss);
        float* tmp = src; src = dst; dst = tmp;
    }

    // conv4 (1x1 gconv) + stats (BN+ReLU fused into final_k)
    conv1x1_k<<<cgrid, 256, 0, stream>>>(src, w4F, dst);
    zero_k<<<1, 64, 0, stream>>>(stats, 32);
    stats_k<<<dim3(16, 64), 256, 0, stream>>>(dst, stats);
    finalize_k<<<1, 64, 0, stream>>>(stats, gbF + 128, gbF + 144, ss);

    // max-project + final 1x1 + sigmoid
    final_k<<<(2 * HW) / 256, 256, 0, stream>>>(dst, ss, fwF, d_out, flag);
}

// Round 3
// 1459.151 us; speedup vs baseline: 50.5482x; 50.5482x over previous
//
#include <hip/hip_runtime.h>
#include <hip/hip_bf16.h>
#include <math.h>

// Activations: planar fp32 [B=2][plane=128][256*256] in ws; between layers NHWC bf16
// [B][256*256][136] (ch = ci*8 + o, padded 128->136 for 16B-aligned rows).
#define HW 65536
#define WID 256
#define NOR 8
#define PLANE_C (NOR * HW)          // 524288
#define PLANE_B (16 * NOR * HW)     // 8388608
#define NELEM (2 * PLANE_B)         // 16777216
#define BN_N 1048576.0f
#define NHWC_STRIDE 136             // shorts per pixel (128 real + 8 pad)

typedef __attribute__((ext_vector_type(8)))  short  short8;
typedef __attribute__((ext_vector_type(16))) float  float16;
typedef __attribute__((ext_vector_type(4)))  float  float4v;

__device__ __forceinline__ float bfv(const __hip_bfloat16 v) { return __bfloat162float(v); }

// ---- runtime dtype detection (bf16 vs fp32 storage), as validated in R2 ----
__global__ void detect_k(const void* __restrict__ x, int* __restrict__ flag) {
    __shared__ int bad;
    if (threadIdx.x == 0) bad = 0;
    __syncthreads();
    const __hip_bfloat16* p = (const __hip_bfloat16*)x;
    for (int i = threadIdx.x; i < 4096; i += 256) {
        float v = __bfloat162float(p[i]);
        if (!(fabsf(v) < 1e4f)) atomicOr(&bad, 1);
    }
    __syncthreads();
    if (threadIdx.x == 0) *flag = bad ? 0 : 1;
}

__global__ void cvt_k(const void* __restrict__ in, float* __restrict__ out, int n,
                      const int* __restrict__ flag) {
    int i = blockIdx.x * blockDim.x + threadIdx.x;
    if (i >= n) return;
    if (*flag)
        out[i] = __bfloat162float(((const __hip_bfloat16*)in)[i]);
    else
        out[i] = ((const float*)in)[i];
}

// ---- bilinear kernel rotation (bit-identical to R2, which passed) ----
__device__ float rot_sample(const float* __restrict__ W, int k, float theta, int i, int j) {
    float c = 0.5f * (float)(k - 1);
    float ys = (float)i - c, xs = (float)j - c;
    float cs = cosf(theta), sn = sinf(theta);
    float sy = cs * ys - sn * xs + c;
    float sx = sn * ys + cs * xs + c;
    float fy = floorf(sy), fx = floorf(sx);
    int y0 = (int)fy, x0 = (int)fx;
    float wy = sy - fy, wx = sx - fx;
    float v00 = (y0 >= 0 && y0 < k && x0 >= 0 && x0 < k)                 ? W[y0 * k + x0]           : 0.f;
    float v01 = (y0 >= 0 && y0 < k && x0 + 1 >= 0 && x0 + 1 < k)         ? W[y0 * k + x0 + 1]       : 0.f;
    float v10 = (y0 + 1 >= 0 && y0 + 1 < k && x0 >= 0 && x0 < k)         ? W[(y0 + 1) * k + x0]     : 0.f;
    float v11 = (y0 + 1 >= 0 && y0 + 1 < k && x0 + 1 >= 0 && x0 + 1 < k) ? W[(y0 + 1) * k + x0 + 1] : 0.f;
    return v00 * (1 - wy) * (1 - wx) + v01 * (1 - wy) * wx
         + v10 * wy * (1 - wx) + v11 * wy * wx;
}

__device__ __forceinline__ float theta_of(int m) {
    return (6.2831855f * (float)m) / 8.0f;
}

__device__ __forceinline__ int mirror(int i) {
    i = i < 0 ? -i : i;
    return i >= WID ? (2 * WID - 2 - i) : i;
}

// ---- weight pack: lift B [n=c*8+o][k=ci*49+dy*7+dx, padded to 160] bf16 ----
__global__ void pack_blift_k(const float* __restrict__ lw, __hip_bfloat16* __restrict__ B) {
    int idx = blockIdx.x * 256 + threadIdx.x;
    if (idx >= 128 * 160) return;
    int n = idx / 160, k = idx % 160;
    float v = 0.f;
    if (k < 147) {
        int c = n >> 3, o = n & 7;
        int ci = k / 49, s = k % 49;
        v = rot_sample(lw + (c * 3 + ci) * 49, 7, theta_of(o), s / 7, s % 7);
    }
    B[idx] = __float2bfloat16(v);
}

// ---- weight pack: gconv Bg[s=dy*5+dx][n=co*8+m][ch=ci*8+o] bf16 ----
__global__ void pack_bg_k(const float* __restrict__ w, __hip_bfloat16* __restrict__ Bg) {
    int idx = blockIdx.x * 256 + threadIdx.x;
    if (idx >= 25 * 128 * 128) return;
    int s = idx >> 14;          // /16384
    int r = idx & 16383;
    int n = r >> 7, ch = r & 127;
    int co = n >> 3, m = n & 7, ci = ch >> 3, o = ch & 7;
    int oo = (o - m + 8) & 7;
    float v = rot_sample(w + ((co * 16 + ci) * 8 + oo) * 25, 5, theta_of(m), s / 5, s % 5);
    Bg[idx] = __float2bfloat16(v);
}

// ---- weight pack: 1x1 B1[n=co*8+m][ch=ci*8+o] bf16 ----
__global__ void pack_b1_k(const float* __restrict__ w4, __hip_bfloat16* __restrict__ B1) {
    int idx = blockIdx.x * 256 + threadIdx.x;
    if (idx >= 128 * 128) return;
    int n = idx >> 7, ch = idx & 127;
    int co = n >> 3, m = n & 7, ci = ch >> 3, o = ch & 7;
    B1[idx] = __float2bfloat16(w4[(co * 16 + ci) * 8 + ((o - m + 8) & 7)]);
}

// ---- lift im2col (one batch): A[px][160] bf16, k = ci*49 + dy*7 + dx ----
__global__ void im2col_lift_k(const float* __restrict__ xb, __hip_bfloat16* __restrict__ A) {
    int idx = blockIdx.x * 256 + threadIdx.x;
    if (idx >= HW * 160) return;
    int px = idx / 160, k = idx % 160;
    float v = 0.f;
    if (k < 147) {
        int ci = k / 49, s = k % 49;
        int gy = mirror((px >> 8) + s / 7 - 3);
        int gx = mirror((px & 255) + s % 7 - 3);
        v = xb[ci * HW + gy * WID + gx];
    }
    A[idx] = __float2bfloat16(v);
}

// ---- generic MFMA GEMM core: wave = 64 px (2 A-groups of 32) x 128 n ----
// A layout per MFMA (32x32x16): lane holds A[m=lane&31][k=(lane>>5)*8+j]
// B: lane holds B[k=(lane>>5)*8+j][n=lane&31];  C/D: col=lane&31, row=(reg&3)+8*(reg>>2)+4*(lane>>5)

// lift GEMM: M=65536 (one b), K=160 (10 ksteps), N=128. out pre-offset by b.
__global__ __launch_bounds__(256, 2) void lift_gemm_k(const __hip_bfloat16* __restrict__ Ah,
                                                      const __hip_bfloat16* __restrict__ Bh,
                                                      float* __restrict__ out) {
    const short* A = (const short*)Ah;
    const short* B = (const short*)Bh;
    int wave = threadIdx.x >> 6, lane = threadIdx.x & 63;
    int l31 = lane & 31, half = lane >> 5;
    int p0 = blockIdx.x * 256 + wave * 64;
    float16 acc[8];
#pragma unroll
    for (int i = 0; i < 8; i++) acc[i] = (float16)0.f;
    const short* a0p = A + (size_t)(p0 + l31) * 160 + half * 8;
    const short* a1p = a0p + 32 * 160;
    const short* bp  = B + (size_t)l31 * 160 + half * 8;
#pragma unroll
    for (int ks = 0; ks < 10; ks++) {
        short8 a0 = *(const short8*)(a0p + ks * 16);
        short8 a1 = *(const short8*)(a1p + ks * 16);
#pragma unroll
        for (int nt = 0; nt < 4; nt++) {
            short8 bb = *(const short8*)(bp + nt * 32 * 160 + ks * 16);
            acc[nt]     = __builtin_amdgcn_mfma_f32_32x32x16_bf16(a0, bb, acc[nt], 0, 0, 0);
            acc[4 + nt] = __builtin_amdgcn_mfma_f32_32x32x16_bf16(a1, bb, acc[4 + nt], 0, 0, 0);
        }
    }
#pragma unroll
    for (int g = 0; g < 2; g++)
#pragma unroll
        for (int nt = 0; nt < 4; nt++) {
            int n = nt * 32 + l31;
#pragma unroll
            for (int r4 = 0; r4 < 4; r4++) {
                int base = 8 * r4 + 4 * half;
                float4v v;
                v[0] = acc[g * 4 + nt][r4 * 4 + 0];
                v[1] = acc[g * 4 + nt][r4 * 4 + 1];
                v[2] = acc[g * 4 + nt][r4 * 4 + 2];
                v[3] = acc[g * 4 + nt][r4 * 4 + 3];
                *(float4v*)(out + (size_t)n * HW + p0 + g * 32 + base) = v;
            }
        }
}

// gconv GEMM: 25 shifts x K=128; A direct from NHWC with mirror indexing.
__global__ __launch_bounds__(256, 2) void gconv_mfma_k(const __hip_bfloat16* __restrict__ nh,
                                                       const __hip_bfloat16* __restrict__ Bgh,
                                                       float* __restrict__ out) {
    const short* nhwc = (const short*)nh;
    const short* Bg = (const short*)Bgh;
    int tile = blockIdx.x;          // 256 tiles of 16x16 px
    int b = blockIdx.y;
    int wave = threadIdx.x >> 6, lane = threadIdx.x & 63;
    int l31 = lane & 31, half = lane >> 5;
    int tx0 = (tile & 15) << 4;
    int ty0 = (tile >> 4) << 4;
    int lx = lane & 15;
    int yy = l31 >> 4;              // row-within-A-group
    float16 acc[8];
#pragma unroll
    for (int i = 0; i < 8; i++) acc[i] = (float16)0.f;
    int xg = tx0 + lx;
    int yg0 = ty0 + wave * 4 + yy;  // group 0 row; group 1 = +2
    const size_t bbase = (size_t)b * HW;

    for (int s = 0; s < 25; s++) {
        int dy = s / 5 - 2, dx = s % 5 - 2;
        int gx = mirror(xg + dx);
        int gy0 = mirror(yg0 + dy);
        int gy1 = mirror(yg0 + 2 + dy);
        const short* arow0 = nhwc + (bbase + gy0 * WID + gx) * NHWC_STRIDE + half * 8;
        const short* arow1 = nhwc + (bbase + gy1 * WID + gx) * NHWC_STRIDE + half * 8;
        const short* brow  = Bg + ((size_t)(s * 128 + l31)) * 128 + half * 8;
#pragma unroll
        for (int ks = 0; ks < 8; ks++) {
            short8 a0 = *(const short8*)(arow0 + ks * 16);
            short8 a1 = *(const short8*)(arow1 + ks * 16);
#pragma unroll
            for (int nt = 0; nt < 4; nt++) {
                short8 bb = *(const short8*)(brow + nt * 32 * 128 + ks * 16);
                acc[nt]     = __builtin_amdgcn_mfma_f32_32x32x16_bf16(a0, bb, acc[nt], 0, 0, 0);
                acc[4 + nt] = __builtin_amdgcn_mfma_f32_32x32x16_bf16(a1, bb, acc[4 + nt], 0, 0, 0);
            }
        }
    }
    const size_t outb = (size_t)b * PLANE_B;
#pragma unroll
    for (int g = 0; g < 2; g++) {
        int ybase = ty0 + wave * 4 + g * 2;
#pragma unroll
        for (int nt = 0; nt < 4; nt++) {
            int n = nt * 32 + l31;
            float* plane = out + outb + (size_t)n * HW;
#pragma unroll
            for (int r4 = 0; r4 < 4; r4++) {
                int base = 8 * r4 + 4 * half;
                float4v v;
                v[0] = acc[g * 4 + nt][r4 * 4 + 0];
                v[1] = acc[g * 4 + nt][r4 * 4 + 1];
                v[2] = acc[g * 4 + nt][r4 * 4 + 2];
                v[3] = acc[g * 4 + nt][r4 * 4 + 3];
                *(float4v*)(plane + (size_t)(ybase + (base >> 4)) * WID + tx0 + (base & 15)) = v;
            }
        }
    }
}

// 1x1 gconv GEMM: K=128 straight from NHWC.
__global__ __launch_bounds__(256, 2) void conv1x1_gemm_k(const __hip_bfloat16* __restrict__ nh,
                                                         const __hip_bfloat16* __restrict__ B1h,
                                                         float* __restrict__ out) {
    const short* nhwc = (const short*)nh;
    const short* B1 = (const short*)B1h;
    int b = blockIdx.y;
    int wave = threadIdx.x >> 6, lane = threadIdx.x & 63;
    int l31 = lane & 31, half = lane >> 5;
    int p0 = blockIdx.x * 256 + wave * 64;
    float16 acc[8];
#pragma unroll
    for (int i = 0; i < 8; i++) acc[i] = (float16)0.f;
    const short* a0p = nhwc + ((size_t)b * HW + p0 + l31) * NHWC_STRIDE + half * 8;
    const short* a1p = a0p + 32 * NHWC_STRIDE;
    const short* bp  = B1 + (size_t)l31 * 128 + half * 8;
#pragma unroll
    for (int ks = 0; ks < 8; ks++) {
        short8 a0 = *(const short8*)(a0p + ks * 16);
        short8 a1 = *(const short8*)(a1p + ks * 16);
#pragma unroll
        for (int nt = 0; nt < 4; nt++) {
            short8 bb = *(const short8*)(bp + nt * 32 * 128 + ks * 16);
            acc[nt]     = __builtin_amdgcn_mfma_f32_32x32x16_bf16(a0, bb, acc[nt], 0, 0, 0);
            acc[4 + nt] = __builtin_amdgcn_mfma_f32_32x32x16_bf16(a1, bb, acc[4 + nt], 0, 0, 0);
        }
    }
    float* outb = out + (size_t)b * PLANE_B;
#pragma unroll
    for (int g = 0; g < 2; g++)
#pragma unroll
        for (int nt = 0; nt < 4; nt++) {
            int n = nt * 32 + l31;
#pragma unroll
            for (int r4 = 0; r4 < 4; r4++) {
                int base = 8 * r4 + 4 * half;
                float4v v;
                v[0] = acc[g * 4 + nt][r4 * 4 + 0];
                v[1] = acc[g * 4 + nt][r4 * 4 + 1];
                v[2] = acc[g * 4 + nt][r4 * 4 + 2];
                v[3] = acc[g * 4 + nt][r4 * 4 + 3];
                *(float4v*)(outb + (size_t)n * HW + p0 + g * 32 + base) = v;
            }
        }
}

// ---- BN batch stats over planar fp32 ----
__global__ void zero_k(float* p, int n) {
    int i = blockIdx.x * blockDim.x + threadIdx.x;
    if (i < n) p[i] = 0.f;
}

__global__ void stats_k(const float* __restrict__ buf, float* __restrict__ stats) {
    int c = blockIdx.x;
    float s = 0.f, s2 = 0.f;
    int total = 2 * NOR * HW;
    for (int i = blockIdx.y * blockDim.x + threadIdx.x; i < total; i += gridDim.y * blockDim.x) {
        int b = i >> 19;
        int rem = i & ((1 << 19) - 1);
        float v = buf[(size_t)b * PLANE_B + (size_t)c * PLANE_C + rem];
        s += v;
        s2 += v * v;
    }
#pragma unroll
    for (int off = 32; off > 0; off >>= 1) {
        s += __shfl_down(s, off);
        s2 += __shfl_down(s2, off);
    }
    __shared__ float ls[4], ls2[4];
    int wid = threadIdx.x >> 6, lid = threadIdx.x & 63;
    if (lid == 0) { ls[wid] = s; ls2[wid] = s2; }
    __syncthreads();
    if (threadIdx.x == 0) {
        atomicAdd(&stats[c * 2], ls[0] + ls[1] + ls[2] + ls[3]);
        atomicAdd(&stats[c * 2 + 1], ls2[0] + ls2[1] + ls2[2] + ls2[3]);
    }
}

__global__ void finalize_k(const float* __restrict__ stats, const float* __restrict__ g,
                           const float* __restrict__ beta, float* __restrict__ ss) {
    int c = threadIdx.x;
    if (c >= 16) return;
    float mean = stats[c * 2] / BN_N;
    float var = stats[c * 2 + 1] / BN_N - mean * mean;
    float sc = g[c] * rsqrtf(var + 1e-5f);
    ss[c * 2] = sc;
    ss[c * 2 + 1] = beta[c] - mean * sc;
}

// ---- fused BN+ReLU + planar->NHWC(bf16, padded) repack ----
__global__ void repack_k(const float* __restrict__ planar, const float* __restrict__ ss,
                         __hip_bfloat16* __restrict__ nhwc) {
    __shared__ __hip_bfloat16 ls[128 * NHWC_STRIDE];
    int b = blockIdx.y;
    int px0 = blockIdx.x * 128;
    for (int i = threadIdx.x; i < 128 * 8; i += 256)
        ls[(i >> 3) * NHWC_STRIDE + 128 + (i & 7)] = __float2bfloat16(0.f);
    int px = threadIdx.x & 127;
    int choff = threadIdx.x >> 7;
    const float* pb = planar + (size_t)b * PLANE_B + px0 + px;
    for (int chb = 0; chb < 64; chb++) {
        int ch = chb * 2 + choff;
        int c = ch >> 3;
        float v = pb[(size_t)ch * HW];
        v = v * ss[c * 2] + ss[c * 2 + 1];
        v = v > 0.f ? v : 0.f;
        ls[px * NHWC_STRIDE + ch] = __float2bfloat16(v);
    }
    __syncthreads();
    short* outp = (short*)nhwc + ((size_t)b * HW + px0) * NHWC_STRIDE;
    const short* lsp = (const short*)ls;
    for (int i = threadIdx.x; i < 128 * 17; i += 256) {
        int p = i / 17, seg = i % 17;
        *(short8*)(outp + (size_t)p * NHWC_STRIDE + seg * 8) =
            *(const short8*)(lsp + p * NHWC_STRIDE + seg * 8);
    }
}

// ---- BN+ReLU on conv4, max over m, final 1x1 + sigmoid; dtype-flagged write ----
__global__ void final_k(const float* __restrict__ in, const float* __restrict__ ss,
                        const float* __restrict__ fw, void* __restrict__ out,
                        const int* __restrict__ flag) {
    int i = blockIdx.x * blockDim.x + threadIdx.x;
    int b = i >> 16, pix = i & 65535;
    float acc = 0.f;
#pragma unroll
    for (int co = 0; co < 16; co++) {
        float sc = ss[co * 2], sh = ss[co * 2 + 1];
        float mx = 0.f;
        const float* p = in + (size_t)b * PLANE_B + (size_t)co * PLANE_C + pix;
#pragma unroll
        for (int m = 0; m < 8; m++) mx = fmaxf(mx, p[m * HW] * sc + sh);
        acc = fmaf(fw[co], mx, acc);
    }
    float r = 1.f / (1.f + expf(-acc));
    if (*flag)
        ((__hip_bfloat16*)out)[i] = __float2bfloat16(r);
    else
        ((float*)out)[i] = r;
}

extern "C" void kernel_launch(void* const* d_in, const int* in_sizes, int n_in,
                              void* d_out, int out_size, void* d_ws, size_t ws_size,
                              hipStream_t stream) {
    float* ws = (float*)d_ws;
    float* planar = ws;                                   // 16,777,216 f
    __hip_bfloat16* nhwc = (__hip_bfloat16*)(ws + 16777216);   // 17,825,792 bf16 (8,912,896 f)
    __hip_bfloat16* Alift = (__hip_bfloat16*)(ws + 25690112);  // 10,485,760 bf16 (5,242,880 f)
    __hip_bfloat16* Bg    = (__hip_bfloat16*)(ws + 30932992);  // 409,600 bf16 (204,800 f)
    __hip_bfloat16* Blift = (__hip_bfloat16*)(ws + 31137792);  // 20,480 bf16 (10,240 f)
    __hip_bfloat16* B1    = (__hip_bfloat16*)(ws + 31148032);  // 16,384 bf16 (8,192 f)
    float* xF  = ws + 31156224;        // 393216
    float* lwF = xF + 393216;          // 2352
    float* w1F = lwF + 2352;           // 102400
    float* w2F = w1F + 102400;
    float* w3F = w2F + 102400;
    float* w4F = w3F + 102400;         // 2048
    float* fwF = w4F + 2048;           // 16
    float* gbF = fwF + 16;             // 160
    float* stats = gbF + 160;          // 32
    float* ss    = stats + 32;         // 32
    int*   flag  = (int*)(ss + 32);

    detect_k<<<1, 256, 0, stream>>>(d_in[0], flag);
    {
        float* dsts[17] = {xF, lwF, w1F, w2F, w3F, w4F, fwF,
                           gbF + 0,  gbF + 16, gbF + 32, gbF + 48, gbF + 64,
                           gbF + 80, gbF + 96, gbF + 112, gbF + 128, gbF + 144};
        for (int i = 0; i < 17; i++) {
            int n = in_sizes[i];
            cvt_k<<<(n + 255) / 256, 256, 0, stream>>>(d_in[i], dsts[i], n, flag);
        }
    }

    // ---- lift: pack B, per-batch im2col + GEMM ----
    pack_blift_k<<<(128 * 160 + 255) / 256, 256, 0, stream>>>(lwF, Blift);
    for (int b = 0; b < 2; b++) {
        im2col_lift_k<<<(HW * 160 + 255) / 256, 256, 0, stream>>>(xF + (size_t)b * 3 * HW, Alift);
        lift_gemm_k<<<256, 256, 0, stream>>>(Alift, Blift, planar + (size_t)b * PLANE_B);
    }
    zero_k<<<1, 64, 0, stream>>>(stats, 32);
    stats_k<<<dim3(16, 64), 256, 0, stream>>>(planar, stats);
    finalize_k<<<1, 64, 0, stream>>>(stats, gbF + 0, gbF + 16, ss);
    repack_k<<<dim3(512, 2), 256, 0, stream>>>(planar, ss, nhwc);

    // ---- gconv 1..3 ----
    float* wlist[3] = {w1F, w2F, w3F};
    for (int l = 0; l < 3; l++) {
        pack_bg_k<<<(25 * 128 * 128 + 255) / 256, 256, 0, stream>>>(wlist[l], Bg);
        gconv_mfma_k<<<dim3(256, 2), 256, 0, stream>>>(nhwc, Bg, planar);
        zero_k<<<1, 64, 0, stream>>>(stats, 32);
        stats_k<<<dim3(16, 64), 256, 0, stream>>>(planar, stats);
        finalize_k<<<1, 64, 0, stream>>>(stats, gbF + 32 * (l + 1), gbF + 32 * (l + 1) + 16, ss);
        repack_k<<<dim3(512, 2), 256, 0, stream>>>(planar, ss, nhwc);
    }

    // ---- conv4 (1x1) + stats (BN/ReLU fused into final_k) ----
    pack_b1_k<<<(128 * 128 + 255) / 256, 256, 0, stream>>>(w4F, B1);
    conv1x1_gemm_k<<<dim3(256, 2), 256, 0, stream>>>(nhwc, B1, planar);
    zero_k<<<1, 64, 0, stream>>>(stats, 32);
    stats_k<<<dim3(16, 64), 256, 0, stream>>>(planar, stats);
    finalize_k<<<1, 64, 0, stream>>>(stats, gbF + 128, gbF + 144, ss);

    // ---- max-project + final 1x1 + sigmoid ----
    final_k<<<(2 * HW) / 256, 256, 0, stream>>>(planar, ss, fwF, d_out, flag);
}

// Round 4
// 1259.053 us; speedup vs baseline: 58.5817x; 1.1589x over previous
//
#include <hip/hip_runtime.h>
#include <hip/hip_bf16.h>
#include <math.h>

// Activations: planar fp32 [B=2][plane=128][256*256] in ws; between layers NHWC bf16
// [B][256*256][136] (ch = ci*8 + o, padded 128->136 for 16B-aligned rows).
#define HW 65536
#define WID 256
#define NOR 8
#define PLANE_C (NOR * HW)          // 524288
#define PLANE_B (16 * NOR * HW)     // 8388608
#define NELEM (2 * PLANE_B)         // 16777216
#define BN_N 1048576.0f
#define NHWC_STRIDE 136             // shorts per pixel (128 real + 8 pad)

typedef __attribute__((ext_vector_type(8)))  short  short8;
typedef __attribute__((ext_vector_type(16))) float  float16;
typedef __attribute__((ext_vector_type(4)))  float  float4v;

__device__ __forceinline__ float bfv(const __hip_bfloat16 v) { return __bfloat162float(v); }

// ---- runtime dtype detection (bf16 vs fp32 storage), validated in R2/R3 ----
__global__ void detect_k(const void* __restrict__ x, int* __restrict__ flag) {
    __shared__ int bad;
    if (threadIdx.x == 0) bad = 0;
    __syncthreads();
    const __hip_bfloat16* p = (const __hip_bfloat16*)x;
    for (int i = threadIdx.x; i < 4096; i += 256) {
        float v = __bfloat162float(p[i]);
        if (!(fabsf(v) < 1e4f)) atomicOr(&bad, 1);
    }
    __syncthreads();
    if (threadIdx.x == 0) *flag = bad ? 0 : 1;
}

__global__ void cvt_k(const void* __restrict__ in, float* __restrict__ out, int n,
                      const int* __restrict__ flag) {
    int i = blockIdx.x * blockDim.x + threadIdx.x;
    if (i >= n) return;
    if (*flag)
        out[i] = __bfloat162float(((const __hip_bfloat16*)in)[i]);
    else
        out[i] = ((const float*)in)[i];
}

// ---- bilinear kernel rotation (bit-identical to R2/R3, which passed) ----
__device__ float rot_sample(const float* __restrict__ W, int k, float theta, int i, int j) {
    float c = 0.5f * (float)(k - 1);
    float ys = (float)i - c, xs = (float)j - c;
    float cs = cosf(theta), sn = sinf(theta);
    float sy = cs * ys - sn * xs + c;
    float sx = sn * ys + cs * xs + c;
    float fy = floorf(sy), fx = floorf(sx);
    int y0 = (int)fy, x0 = (int)fx;
    float wy = sy - fy, wx = sx - fx;
    float v00 = (y0 >= 0 && y0 < k && x0 >= 0 && x0 < k)                 ? W[y0 * k + x0]           : 0.f;
    float v01 = (y0 >= 0 && y0 < k && x0 + 1 >= 0 && x0 + 1 < k)         ? W[y0 * k + x0 + 1]       : 0.f;
    float v10 = (y0 + 1 >= 0 && y0 + 1 < k && x0 >= 0 && x0 < k)         ? W[(y0 + 1) * k + x0]     : 0.f;
    float v11 = (y0 + 1 >= 0 && y0 + 1 < k && x0 + 1 >= 0 && x0 + 1 < k) ? W[(y0 + 1) * k + x0 + 1] : 0.f;
    return v00 * (1 - wy) * (1 - wx) + v01 * (1 - wy) * wx
         + v10 * wy * (1 - wx) + v11 * wy * wx;
}

__device__ __forceinline__ float theta_of(int m) {
    return (6.2831855f * (float)m) / 8.0f;
}

__device__ __forceinline__ int mirror(int i) {
    i = i < 0 ? -i : i;
    return i >= WID ? (2 * WID - 2 - i) : i;
}

// ---- weight pack: lift B [n=c*8+o][k=ci*49+dy*7+dx, padded to 160] bf16 ----
__global__ void pack_blift_k(const float* __restrict__ lw, __hip_bfloat16* __restrict__ B) {
    int idx = blockIdx.x * 256 + threadIdx.x;
    if (idx >= 128 * 160) return;
    int n = idx / 160, k = idx % 160;
    float v = 0.f;
    if (k < 147) {
        int c = n >> 3, o = n & 7;
        int ci = k / 49, s = k % 49;
        v = rot_sample(lw + (c * 3 + ci) * 49, 7, theta_of(o), s / 7, s % 7);
    }
    B[idx] = __float2bfloat16(v);
}

// ---- weight pack: gconv Bg[s=dy*5+dx][n=co*8+m][ch=ci*8+o] bf16 ----
__global__ void pack_bg_k(const float* __restrict__ w, __hip_bfloat16* __restrict__ Bg) {
    int idx = blockIdx.x * 256 + threadIdx.x;
    if (idx >= 25 * 128 * 128) return;
    int s = idx >> 14;
    int r = idx & 16383;
    int n = r >> 7, ch = r & 127;
    int co = n >> 3, m = n & 7, ci = ch >> 3, o = ch & 7;
    int oo = (o - m + 8) & 7;
    float v = rot_sample(w + ((co * 16 + ci) * 8 + oo) * 25, 5, theta_of(m), s / 5, s % 5);
    Bg[idx] = __float2bfloat16(v);
}

// ---- weight pack: 1x1 B1[n=co*8+m][ch=ci*8+o] bf16 ----
__global__ void pack_b1_k(const float* __restrict__ w4, __hip_bfloat16* __restrict__ B1) {
    int idx = blockIdx.x * 256 + threadIdx.x;
    if (idx >= 128 * 128) return;
    int n = idx >> 7, ch = idx & 127;
    int co = n >> 3, m = n & 7, ci = ch >> 3, o = ch & 7;
    B1[idx] = __float2bfloat16(w4[(co * 16 + ci) * 8 + ((o - m + 8) & 7)]);
}

// ---- lift im2col (one batch): A[px][160] bf16, k = ci*49 + dy*7 + dx ----
__global__ void im2col_lift_k(const float* __restrict__ xb, __hip_bfloat16* __restrict__ A) {
    int idx = blockIdx.x * 256 + threadIdx.x;
    if (idx >= HW * 160) return;
    int px = idx / 160, k = idx % 160;
    float v = 0.f;
    if (k < 147) {
        int ci = k / 49, s = k % 49;
        int gy = mirror((px >> 8) + s / 7 - 3);
        int gx = mirror((px & 255) + s % 7 - 3);
        v = xb[ci * HW + gy * WID + gx];
    }
    A[idx] = __float2bfloat16(v);
}

// ---- MFMA fragment conventions (verified R3):
// A (32x32x16): lane holds A[m=lane&31][k=(lane>>5)*8+j]
// B: lane holds B[k=(lane>>5)*8+j][n=lane&31]
// C/D: col=lane&31, row=(reg&3)+8*(reg>>2)+4*(lane>>5)

// lift GEMM: M=65536 (one b), K=160 (10 ksteps), N=128. out pre-offset by b.
__global__ __launch_bounds__(256, 2) void lift_gemm_k(const __hip_bfloat16* __restrict__ Ah,
                                                      const __hip_bfloat16* __restrict__ Bh,
                                                      float* __restrict__ out) {
    const short* A = (const short*)Ah;
    const short* B = (const short*)Bh;
    int wave = threadIdx.x >> 6, lane = threadIdx.x & 63;
    int l31 = lane & 31, half = lane >> 5;
    int p0 = blockIdx.x * 256 + wave * 64;
    float16 acc[8];
#pragma unroll
    for (int i = 0; i < 8; i++) acc[i] = (float16)0.f;
    const short* a0p = A + (size_t)(p0 + l31) * 160 + half * 8;
    const short* a1p = a0p + 32 * 160;
    const short* bp  = B + (size_t)l31 * 160 + half * 8;
#pragma unroll
    for (int ks = 0; ks < 10; ks++) {
        short8 a0 = *(const short8*)(a0p + ks * 16);
        short8 a1 = *(const short8*)(a1p + ks * 16);
#pragma unroll
        for (int nt = 0; nt < 4; nt++) {
            short8 bb = *(const short8*)(bp + nt * 32 * 160 + ks * 16);
            acc[nt]     = __builtin_amdgcn_mfma_f32_32x32x16_bf16(a0, bb, acc[nt], 0, 0, 0);
            acc[4 + nt] = __builtin_amdgcn_mfma_f32_32x32x16_bf16(a1, bb, acc[4 + nt], 0, 0, 0);
        }
    }
#pragma unroll
    for (int g = 0; g < 2; g++)
#pragma unroll
        for (int nt = 0; nt < 4; nt++) {
            int n = nt * 32 + l31;
#pragma unroll
            for (int r4 = 0; r4 < 4; r4++) {
                int base = 8 * r4 + 4 * half;
                float4v v;
                v[0] = acc[g * 4 + nt][r4 * 4 + 0];
                v[1] = acc[g * 4 + nt][r4 * 4 + 1];
                v[2] = acc[g * 4 + nt][r4 * 4 + 2];
                v[3] = acc[g * 4 + nt][r4 * 4 + 3];
                *(float4v*)(out + (size_t)n * HW + p0 + g * 32 + base) = v;
            }
        }
}

// gconv GEMM, R4 retile: 1024 blocks; wave = 64 px x 64 n (4 acc -> 4 waves/SIMD);
// XCD y-band swizzle: bid&7 selects (batch, 64-row band) so each XCD's L2 holds
// one ~4.4 MB activation band across all 25 shifts.
__global__ __launch_bounds__(256, 4) void gconv_mfma_k(const __hip_bfloat16* __restrict__ nh,
                                                       const __hip_bfloat16* __restrict__ Bgh,
                                                       float* __restrict__ out) {
    const short* nhwc = (const short*)nh;
    const short* Bg = (const short*)Bgh;
    int bid = blockIdx.x;           // 0..1023
    int xcd = bid & 7;
    int q   = bid >> 3;             // 0..127
    int b    = xcd >> 2;            // batch
    int band = xcd & 3;             // 64-row y-band
    int nhalf = q & 1;
    int rest = q >> 1;              // 0..63
    int tx0 = (rest & 15) << 4;
    int ty0 = (band << 6) + ((rest >> 4) << 4);
    int wave = threadIdx.x >> 6, lane = threadIdx.x & 63;
    int l31 = lane & 31, half = lane >> 5;
    int lx = lane & 15;
    int yy = l31 >> 4;
    float16 acc[4];
#pragma unroll
    for (int i = 0; i < 4; i++) acc[i] = (float16)0.f;
    int xg = tx0 + lx;
    int yg0 = ty0 + wave * 4 + yy;  // group 0 rows; group 1 = +2
    const size_t bbase = (size_t)b * HW;
    const int nbase = nhalf * 64;

    for (int s = 0; s < 25; s++) {
        int dy = s / 5 - 2, dx = s % 5 - 2;
        int gx = mirror(xg + dx);
        int gy0 = mirror(yg0 + dy);
        int gy1 = mirror(yg0 + 2 + dy);
        const short* arow0 = nhwc + (bbase + gy0 * WID + gx) * NHWC_STRIDE + half * 8;
        const short* arow1 = nhwc + (bbase + gy1 * WID + gx) * NHWC_STRIDE + half * 8;
        const short* brow  = Bg + ((size_t)(s * 128 + nbase + l31)) * 128 + half * 8;
#pragma unroll
        for (int ks = 0; ks < 8; ks++) {
            short8 a0 = *(const short8*)(arow0 + ks * 16);
            short8 a1 = *(const short8*)(arow1 + ks * 16);
#pragma unroll
            for (int nt = 0; nt < 2; nt++) {
                short8 bb = *(const short8*)(brow + nt * 32 * 128 + ks * 16);
                acc[nt]     = __builtin_amdgcn_mfma_f32_32x32x16_bf16(a0, bb, acc[nt], 0, 0, 0);
                acc[2 + nt] = __builtin_amdgcn_mfma_f32_32x32x16_bf16(a1, bb, acc[2 + nt], 0, 0, 0);
            }
        }
    }
    const size_t outb = (size_t)b * PLANE_B;
#pragma unroll
    for (int g = 0; g < 2; g++) {
        int ybase = ty0 + wave * 4 + g * 2;
#pragma unroll
        for (int nt = 0; nt < 2; nt++) {
            int n = nbase + nt * 32 + l31;
            float* plane = out + outb + (size_t)n * HW;
#pragma unroll
            for (int r4 = 0; r4 < 4; r4++) {
                int base = 8 * r4 + 4 * half;
                float4v v;
                v[0] = acc[g * 2 + nt][r4 * 4 + 0];
                v[1] = acc[g * 2 + nt][r4 * 4 + 1];
                v[2] = acc[g * 2 + nt][r4 * 4 + 2];
                v[3] = acc[g * 2 + nt][r4 * 4 + 3];
                *(float4v*)(plane + (size_t)(ybase + (base >> 4)) * WID + tx0 + (base & 15)) = v;
            }
        }
    }
}

// 1x1 gconv GEMM: K=128 straight from NHWC.
__global__ __launch_bounds__(256, 2) void conv1x1_gemm_k(const __hip_bfloat16* __restrict__ nh,
                                                         const __hip_bfloat16* __restrict__ B1h,
                                                         float* __restrict__ out) {
    const short* nhwc = (const short*)nh;
    const short* B1 = (const short*)B1h;
    int b = blockIdx.y;
    int wave = threadIdx.x >> 6, lane = threadIdx.x & 63;
    int l31 = lane & 31, half = lane >> 5;
    int p0 = blockIdx.x * 256 + wave * 64;
    float16 acc[8];
#pragma unroll
    for (int i = 0; i < 8; i++) acc[i] = (float16)0.f;
    const short* a0p = nhwc + ((size_t)b * HW + p0 + l31) * NHWC_STRIDE + half * 8;
    const short* a1p = a0p + 32 * NHWC_STRIDE;
    const short* bp  = B1 + (size_t)l31 * 128 + half * 8;
#pragma unroll
    for (int ks = 0; ks < 8; ks++) {
        short8 a0 = *(const short8*)(a0p + ks * 16);
        short8 a1 = *(const short8*)(a1p + ks * 16);
#pragma unroll
        for (int nt = 0; nt < 4; nt++) {
            short8 bb = *(const short8*)(bp + nt * 32 * 128 + ks * 16);
            acc[nt]     = __builtin_amdgcn_mfma_f32_32x32x16_bf16(a0, bb, acc[nt], 0, 0, 0);
            acc[4 + nt] = __builtin_amdgcn_mfma_f32_32x32x16_bf16(a1, bb, acc[4 + nt], 0, 0, 0);
        }
    }
    float* outb = out + (size_t)b * PLANE_B;
#pragma unroll
    for (int g = 0; g < 2; g++)
#pragma unroll
        for (int nt = 0; nt < 4; nt++) {
            int n = nt * 32 + l31;
#pragma unroll
            for (int r4 = 0; r4 < 4; r4++) {
                int base = 8 * r4 + 4 * half;
                float4v v;
                v[0] = acc[g * 4 + nt][r4 * 4 + 0];
                v[1] = acc[g * 4 + nt][r4 * 4 + 1];
                v[2] = acc[g * 4 + nt][r4 * 4 + 2];
                v[3] = acc[g * 4 + nt][r4 * 4 + 3];
                *(float4v*)(outb + (size_t)n * HW + p0 + g * 32 + base) = v;
            }
        }
}

// ---- BN batch stats over planar fp32 ----
__global__ void zero_k(float* p, int n) {
    int i = blockIdx.x * blockDim.x + threadIdx.x;
    if (i < n) p[i] = 0.f;
}

__global__ void stats_k(const float* __restrict__ buf, float* __restrict__ stats) {
    int c = blockIdx.x;
    float s = 0.f, s2 = 0.f;
    int total = 2 * NOR * HW;
    for (int i = blockIdx.y * blockDim.x + threadIdx.x; i < total; i += gridDim.y * blockDim.x) {
        int b = i >> 19;
        int rem = i & ((1 << 19) - 1);
        float v = buf[(size_t)b * PLANE_B + (size_t)c * PLANE_C + rem];
        s += v;
        s2 += v * v;
    }
#pragma unroll
    for (int off = 32; off > 0; off >>= 1) {
        s += __shfl_down(s, off);
        s2 += __shfl_down(s2, off);
    }
    __shared__ float ls[4], ls2[4];
    int wid = threadIdx.x >> 6, lid = threadIdx.x & 63;
    if (lid == 0) { ls[wid] = s; ls2[wid] = s2; }
    __syncthreads();
    if (threadIdx.x == 0) {
        atomicAdd(&stats[c * 2], ls[0] + ls[1] + ls[2] + ls[3]);
        atomicAdd(&stats[c * 2 + 1], ls2[0] + ls2[1] + ls2[2] + ls2[3]);
    }
}

__global__ void finalize_k(const float* __restrict__ stats, const float* __restrict__ g,
                           const float* __restrict__ beta, float* __restrict__ ss) {
    int c = threadIdx.x;
    if (c >= 16) return;
    float mean = stats[c * 2] / BN_N;
    float var = stats[c * 2 + 1] / BN_N - mean * mean;
    float sc = g[c] * rsqrtf(var + 1e-5f);
    ss[c * 2] = sc;
    ss[c * 2 + 1] = beta[c] - mean * sc;
}

// ---- fused BN+ReLU + planar->NHWC(bf16, padded) repack ----
__global__ void repack_k(const float* __restrict__ planar, const float* __restrict__ ss,
                         __hip_bfloat16* __restrict__ nhwc) {
    __shared__ __hip_bfloat16 ls[128 * NHWC_STRIDE];
    int b = blockIdx.y;
    int px0 = blockIdx.x * 128;
    for (int i = threadIdx.x; i < 128 * 8; i += 256)
        ls[(i >> 3) * NHWC_STRIDE + 128 + (i & 7)] = __float2bfloat16(0.f);
    int px = threadIdx.x & 127;
    int choff = threadIdx.x >> 7;
    const float* pb = planar + (size_t)b * PLANE_B + px0 + px;
    for (int chb = 0; chb < 64; chb++) {
        int ch = chb * 2 + choff;
        int c = ch >> 3;
        float v = pb[(size_t)ch * HW];
        v = v * ss[c * 2] + ss[c * 2 + 1];
        v = v > 0.f ? v : 0.f;
        ls[px * NHWC_STRIDE + ch] = __float2bfloat16(v);
    }
    __syncthreads();
    short* outp = (short*)nhwc + ((size_t)b * HW + px0) * NHWC_STRIDE;
    const short* lsp = (const short*)ls;
    for (int i = threadIdx.x; i < 128 * 17; i += 256) {
        int p = i / 17, seg = i % 17;
        *(short8*)(outp + (size_t)p * NHWC_STRIDE + seg * 8) =
            *(const short8*)(lsp + p * NHWC_STRIDE + seg * 8);
    }
}

// ---- BN+ReLU on conv4, max over m, final 1x1 + sigmoid; dtype-flagged write ----
__global__ void final_k(const float* __restrict__ in, const float* __restrict__ ss,
                        const float* __restrict__ fw, void* __restrict__ out,
                        const int* __restrict__ flag) {
    int i = blockIdx.x * blockDim.x + threadIdx.x;
    int b = i >> 16, pix = i & 65535;
    float acc = 0.f;
#pragma unroll
    for (int co = 0; co < 16; co++) {
        float sc = ss[co * 2], sh = ss[co * 2 + 1];
        float mx = 0.f;
        const float* p = in + (size_t)b * PLANE_B + (size_t)co * PLANE_C + pix;
#pragma unroll
        for (int m = 0; m < 8; m++) mx = fmaxf(mx, p[m * HW] * sc + sh);
        acc = fmaf(fw[co], mx, acc);
    }
    float r = 1.f / (1.f + expf(-acc));
    if (*flag)
        ((__hip_bfloat16*)out)[i] = __float2bfloat16(r);
    else
        ((float*)out)[i] = r;
}

extern "C" void kernel_launch(void* const* d_in, const int* in_sizes, int n_in,
                              void* d_out, int out_size, void* d_ws, size_t ws_size,
                              hipStream_t stream) {
    float* ws = (float*)d_ws;
    float* planar = ws;                                        // 16,777,216 f
    __hip_bfloat16* nhwc = (__hip_bfloat16*)(ws + 16777216);   // 17,825,792 bf16
    __hip_bfloat16* Alift = (__hip_bfloat16*)(ws + 25690112);  // 10,485,760 bf16
    __hip_bfloat16* Bg    = (__hip_bfloat16*)(ws + 30932992);  // 409,600 bf16
    __hip_bfloat16* Blift = (__hip_bfloat16*)(ws + 31137792);  // 20,480 bf16
    __hip_bfloat16* B1    = (__hip_bfloat16*)(ws + 31148032);  // 16,384 bf16
    float* xF  = ws + 31156224;        // 393216
    float* lwF = xF + 393216;          // 2352
    float* w1F = lwF + 2352;           // 102400
    float* w2F = w1F + 102400;
    float* w3F = w2F + 102400;
    float* w4F = w3F + 102400;         // 2048
    float* fwF = w4F + 2048;           // 16
    float* gbF = fwF + 16;             // 160
    float* stats = gbF + 160;          // 32
    float* ss    = stats + 32;         // 32
    int*   flag  = (int*)(ss + 32);

    detect_k<<<1, 256, 0, stream>>>(d_in[0], flag);
    {
        float* dsts[17] = {xF, lwF, w1F, w2F, w3F, w4F, fwF,
                           gbF + 0,  gbF + 16, gbF + 32, gbF + 48, gbF + 64,
                           gbF + 80, gbF + 96, gbF + 112, gbF + 128, gbF + 144};
        for (int i = 0; i < 17; i++) {
            int n = in_sizes[i];
            cvt_k<<<(n + 255) / 256, 256, 0, stream>>>(d_in[i], dsts[i], n, flag);
        }
    }

    // ---- lift: pack B, per-batch im2col + GEMM ----
    pack_blift_k<<<(128 * 160 + 255) / 256, 256, 0, stream>>>(lwF, Blift);
    for (int b = 0; b < 2; b++) {
        im2col_lift_k<<<(HW * 160 + 255) / 256, 256, 0, stream>>>(xF + (size_t)b * 3 * HW, Alift);
        lift_gemm_k<<<256, 256, 0, stream>>>(Alift, Blift, planar + (size_t)b * PLANE_B);
    }
    zero_k<<<1, 64, 0, stream>>>(stats, 32);
    stats_k<<<dim3(16, 64), 256, 0, stream>>>(planar, stats);
    finalize_k<<<1, 64, 0, stream>>>(stats, gbF + 0, gbF + 16, ss);
    repack_k<<<dim3(512, 2), 256, 0, stream>>>(planar, ss, nhwc);

    // ---- gconv 1..3 ----
    float* wlist[3] = {w1F, w2F, w3F};
    for (int l = 0; l < 3; l++) {
        pack_bg_k<<<(25 * 128 * 128 + 255) / 256, 256, 0, stream>>>(wlist[l], Bg);
        gconv_mfma_k<<<1024, 256, 0, stream>>>(nhwc, Bg, planar);
        zero_k<<<1, 64, 0, stream>>>(stats, 32);
        stats_k<<<dim3(16, 64), 256, 0, stream>>>(planar, stats);
        finalize_k<<<1, 64, 0, stream>>>(stats, gbF + 32 * (l + 1), gbF + 32 * (l + 1) + 16, ss);
        repack_k<<<dim3(512, 2), 256, 0, stream>>>(planar, ss, nhwc);
    }

    // ---- conv4 (1x1) + stats (BN/ReLU fused into final_k) ----
    pack_b1_k<<<(128 * 128 + 255) / 256, 256, 0, stream>>>(w4F, B1);
    conv1x1_gemm_k<<<dim3(256, 2), 256, 0, stream>>>(nhwc, B1, planar);
    zero_k<<<1, 64, 0, stream>>>(stats, 32);
    stats_k<<<dim3(16, 64), 256, 0, stream>>>(planar, stats);
    finalize_k<<<1, 64, 0, stream>>>(stats, gbF + 128, gbF + 144, ss);

    // ---- max-project + final 1x1 + sigmoid ----
    final_k<<<(2 * HW) / 256, 256, 0, stream>>>(planar, ss, fwF, d_out, flag);
}

// Round 5
// 1003.766 us; speedup vs baseline: 73.4808x; 1.2543x over previous
//
#include <hip/hip_runtime.h>
#include <hip/hip_bf16.h>
#include <math.h>

// Activations: planar fp32 [B=2][plane=128][256*256] in ws; between layers NHWC bf16
// [B][256*256][136] (ch = ci*8 + o, padded 128->136 for 16B-aligned rows).
#define HW 65536
#define WID 256
#define NOR 8
#define PLANE_C (NOR * HW)          // 524288
#define PLANE_B (16 * NOR * HW)     // 8388608
#define NELEM (2 * PLANE_B)         // 16777216
#define BN_N 1048576.0f
#define NHWC_STRIDE 136             // shorts per pixel (128 real + 8 pad)

typedef __attribute__((ext_vector_type(8)))  short  short8;
typedef __attribute__((ext_vector_type(16))) float  float16;
typedef __attribute__((ext_vector_type(4)))  float  float4v;

__device__ __forceinline__ float bfv(const __hip_bfloat16 v) { return __bfloat162float(v); }

// ---- runtime dtype detection (bf16 vs fp32 storage), validated in R2/R3 ----
__global__ void detect_k(const void* __restrict__ x, int* __restrict__ flag) {
    __shared__ int bad;
    if (threadIdx.x == 0) bad = 0;
    __syncthreads();
    const __hip_bfloat16* p = (const __hip_bfloat16*)x;
    for (int i = threadIdx.x; i < 4096; i += 256) {
        float v = __bfloat162float(p[i]);
        if (!(fabsf(v) < 1e4f)) atomicOr(&bad, 1);
    }
    __syncthreads();
    if (threadIdx.x == 0) *flag = bad ? 0 : 1;
}

__global__ void cvt_k(const void* __restrict__ in, float* __restrict__ out, int n,
                      const int* __restrict__ flag) {
    int i = blockIdx.x * blockDim.x + threadIdx.x;
    if (i >= n) return;
    if (*flag)
        out[i] = __bfloat162float(((const __hip_bfloat16*)in)[i]);
    else
        out[i] = ((const float*)in)[i];
}

// ---- bilinear kernel rotation (bit-identical to R2..R4, which passed) ----
__device__ float rot_sample(const float* __restrict__ W, int k, float theta, int i, int j) {
    float c = 0.5f * (float)(k - 1);
    float ys = (float)i - c, xs = (float)j - c;
    float cs = cosf(theta), sn = sinf(theta);
    float sy = cs * ys - sn * xs + c;
    float sx = sn * ys + cs * xs + c;
    float fy = floorf(sy), fx = floorf(sx);
    int y0 = (int)fy, x0 = (int)fx;
    float wy = sy - fy, wx = sx - fx;
    float v00 = (y0 >= 0 && y0 < k && x0 >= 0 && x0 < k)                 ? W[y0 * k + x0]           : 0.f;
    float v01 = (y0 >= 0 && y0 < k && x0 + 1 >= 0 && x0 + 1 < k)         ? W[y0 * k + x0 + 1]       : 0.f;
    float v10 = (y0 + 1 >= 0 && y0 + 1 < k && x0 >= 0 && x0 < k)         ? W[(y0 + 1) * k + x0]     : 0.f;
    float v11 = (y0 + 1 >= 0 && y0 + 1 < k && x0 + 1 >= 0 && x0 + 1 < k) ? W[(y0 + 1) * k + x0 + 1] : 0.f;
    return v00 * (1 - wy) * (1 - wx) + v01 * (1 - wy) * wx
         + v10 * wy * (1 - wx) + v11 * wy * wx;
}

__device__ __forceinline__ float theta_of(int m) {
    return (6.2831855f * (float)m) / 8.0f;
}

__device__ __forceinline__ int mirror(int i) {
    i = i < 0 ? -i : i;
    return i >= WID ? (2 * WID - 2 - i) : i;
}

// ---- weight pack: lift B [n=c*8+o][k=ci*49+dy*7+dx, padded to 160] bf16 ----
__global__ void pack_blift_k(const float* __restrict__ lw, __hip_bfloat16* __restrict__ B) {
    int idx = blockIdx.x * 256 + threadIdx.x;
    if (idx >= 128 * 160) return;
    int n = idx / 160, k = idx % 160;
    float v = 0.f;
    if (k < 147) {
        int c = n >> 3, o = n & 7;
        int ci = k / 49, s = k % 49;
        v = rot_sample(lw + (c * 3 + ci) * 49, 7, theta_of(o), s / 7, s % 7);
    }
    B[idx] = __float2bfloat16(v);
}

// ---- weight pack: gconv Bg[s=dy*5+dx][n=co*8+m][ch=ci*8+o] bf16 ----
__global__ void pack_bg_k(const float* __restrict__ w, __hip_bfloat16* __restrict__ Bg) {
    int idx = blockIdx.x * 256 + threadIdx.x;
    if (idx >= 25 * 128 * 128) return;
    int s = idx >> 14;
    int r = idx & 16383;
    int n = r >> 7, ch = r & 127;
    int co = n >> 3, m = n & 7, ci = ch >> 3, o = ch & 7;
    int oo = (o - m + 8) & 7;
    float v = rot_sample(w + ((co * 16 + ci) * 8 + oo) * 25, 5, theta_of(m), s / 5, s % 5);
    Bg[idx] = __float2bfloat16(v);
}

// ---- weight pack: 1x1 B1[n=co*8+m][ch=ci*8+o] bf16 ----
__global__ void pack_b1_k(const float* __restrict__ w4, __hip_bfloat16* __restrict__ B1) {
    int idx = blockIdx.x * 256 + threadIdx.x;
    if (idx >= 128 * 128) return;
    int n = idx >> 7, ch = idx & 127;
    int co = n >> 3, m = n & 7, ci = ch >> 3, o = ch & 7;
    B1[idx] = __float2bfloat16(w4[(co * 16 + ci) * 8 + ((o - m + 8) & 7)]);
}

// ---- lift im2col (one batch): A[px][160] bf16, k = ci*49 + dy*7 + dx ----
__global__ void im2col_lift_k(const float* __restrict__ xb, __hip_bfloat16* __restrict__ A) {
    int idx = blockIdx.x * 256 + threadIdx.x;
    if (idx >= HW * 160) return;
    int px = idx / 160, k = idx % 160;
    float v = 0.f;
    if (k < 147) {
        int ci = k / 49, s = k % 49;
        int gy = mirror((px >> 8) + s / 7 - 3);
        int gx = mirror((px & 255) + s % 7 - 3);
        v = xb[ci * HW + gy * WID + gx];
    }
    A[idx] = __float2bfloat16(v);
}

// ---- MFMA fragment conventions (verified R3/R4):
// A (32x32x16): lane holds A[m=lane&31][k=(lane>>5)*8+j]
// B: lane holds B[k=(lane>>5)*8+j][n=lane&31]
// C/D: col=lane&31, row=(reg&3)+8*(reg>>2)+4*(lane>>5)

// lift GEMM: M=65536 (one b), K=160 (10 ksteps), N=128. out pre-offset by b.
__global__ __launch_bounds__(256, 2) void lift_gemm_k(const __hip_bfloat16* __restrict__ Ah,
                                                      const __hip_bfloat16* __restrict__ Bh,
                                                      float* __restrict__ out) {
    const short* A = (const short*)Ah;
    const short* B = (const short*)Bh;
    int wave = threadIdx.x >> 6, lane = threadIdx.x & 63;
    int l31 = lane & 31, half = lane >> 5;
    int p0 = blockIdx.x * 256 + wave * 64;
    float16 acc[8];
#pragma unroll
    for (int i = 0; i < 8; i++) acc[i] = (float16)0.f;
    const short* a0p = A + (size_t)(p0 + l31) * 160 + half * 8;
    const short* a1p = a0p + 32 * 160;
    const short* bp  = B + (size_t)l31 * 160 + half * 8;
#pragma unroll
    for (int ks = 0; ks < 10; ks++) {
        short8 a0 = *(const short8*)(a0p + ks * 16);
        short8 a1 = *(const short8*)(a1p + ks * 16);
#pragma unroll
        for (int nt = 0; nt < 4; nt++) {
            short8 bb = *(const short8*)(bp + nt * 32 * 160 + ks * 16);
            acc[nt]     = __builtin_amdgcn_mfma_f32_32x32x16_bf16(a0, bb, acc[nt], 0, 0, 0);
            acc[4 + nt] = __builtin_amdgcn_mfma_f32_32x32x16_bf16(a1, bb, acc[4 + nt], 0, 0, 0);
        }
    }
#pragma unroll
    for (int g = 0; g < 2; g++)
#pragma unroll
        for (int nt = 0; nt < 4; nt++) {
            int n = nt * 32 + l31;
#pragma unroll
            for (int r4 = 0; r4 < 4; r4++) {
                int base = 8 * r4 + 4 * half;
                float4v v;
                v[0] = acc[g * 4 + nt][r4 * 4 + 0];
                v[1] = acc[g * 4 + nt][r4 * 4 + 1];
                v[2] = acc[g * 4 + nt][r4 * 4 + 2];
                v[3] = acc[g * 4 + nt][r4 * 4 + 3];
                *(float4v*)(out + (size_t)n * HW + p0 + g * 32 + base) = v;
            }
        }
}

// gconv GEMM R5: 512 blocks (XCD band swizzle), block = 16x16 px x 128 n.
// Wave = 64 px (rows 4w..4w+3 as 2 A-groups) x all 128 n -> 8 acc (128 AGPR).
// B staged in LDS per shift, double-buffered, layout [k8][n][8] (conflict-free,
// 16B aligned). A direct from NHWC (band-L2-hot). launch_bounds(256,2) frees
// VGPRs so the compiler keeps all 16 A-frags of a shift in flight.
__global__ __launch_bounds__(256, 2) void gconv_mfma_k(const __hip_bfloat16* __restrict__ nh,
                                                       const __hip_bfloat16* __restrict__ Bgh,
                                                       float* __restrict__ out) {
    __shared__ short Bs[2][16384];  // 64 KB: [buf][(k8*128+n)*8]
    const short* nhwc = (const short*)nh;
    const short* Bg = (const short*)Bgh;
    int bid = blockIdx.x;           // 0..511
    int xcd = bid & 7;
    int q   = bid >> 3;             // 0..63 tile-in-band
    int b    = xcd >> 2;
    int band = xcd & 3;
    int tx0 = (q & 15) << 4;
    int ty0 = (band << 6) + ((q >> 4) << 4);
    int wave = threadIdx.x >> 6, lane = threadIdx.x & 63;
    int l31 = lane & 31, half = lane >> 5;
    int lx = lane & 15, yy = l31 >> 4;
    float16 acc[8];
#pragma unroll
    for (int i = 0; i < 8; i++) acc[i] = (float16)0.f;
    int xg = tx0 + lx;
    int yg0 = ty0 + (wave << 2) + yy;   // group0 rows; group1 = +2
    const size_t bbase = (size_t)b * HW;

    // stage shift s's B slab (32 KB) into Bs[buf]: chunk c = k8*128+n
    auto stage = [&](int s, int buf) {
        const short* src = Bg + s * 16384;
        short* dstb = &Bs[buf][0];
#pragma unroll
        for (int j = 0; j < 8; j++) {
            int c = threadIdx.x + (j << 8);
            int n = c & 127, k8 = c >> 7;
            *(short8*)(dstb + c * 8) = *(const short8*)(src + n * 128 + k8 * 8);
        }
    };

    stage(0, 0);
    __syncthreads();
    for (int s = 0; s < 25; s++) {
        if (s < 24) stage(s + 1, (s + 1) & 1);
        const short* bsp = &Bs[s & 1][0];
        int dy = s / 5 - 2, dx = s % 5 - 2;
        int gx = mirror(xg + dx);
        int gy0 = mirror(yg0 + dy);
        int gy1 = mirror(yg0 + 2 + dy);
        const short* arow0 = nhwc + (bbase + gy0 * WID + gx) * NHWC_STRIDE + half * 8;
        const short* arow1 = nhwc + (bbase + gy1 * WID + gx) * NHWC_STRIDE + half * 8;
#pragma unroll
        for (int ks = 0; ks < 8; ks++) {
            short8 a0 = *(const short8*)(arow0 + ks * 16);
            short8 a1 = *(const short8*)(arow1 + ks * 16);
#pragma unroll
            for (int nt = 0; nt < 4; nt++) {
                short8 bb = *(const short8*)(bsp + ((ks * 2 + half) * 128 + nt * 32 + l31) * 8);
                acc[nt]     = __builtin_amdgcn_mfma_f32_32x32x16_bf16(a0, bb, acc[nt], 0, 0, 0);
                acc[4 + nt] = __builtin_amdgcn_mfma_f32_32x32x16_bf16(a1, bb, acc[4 + nt], 0, 0, 0);
            }
        }
        __syncthreads();
    }
    const size_t outb = (size_t)b * PLANE_B;
#pragma unroll
    for (int g = 0; g < 2; g++) {
        int ybase = ty0 + (wave << 2) + g * 2;
#pragma unroll
        for (int nt = 0; nt < 4; nt++) {
            int n = nt * 32 + l31;
            float* plane = out + outb + (size_t)n * HW;
#pragma unroll
            for (int r4 = 0; r4 < 4; r4++) {
                int base = 8 * r4 + 4 * half;
                float4v v;
                v[0] = acc[g * 4 + nt][r4 * 4 + 0];
                v[1] = acc[g * 4 + nt][r4 * 4 + 1];
                v[2] = acc[g * 4 + nt][r4 * 4 + 2];
                v[3] = acc[g * 4 + nt][r4 * 4 + 3];
                *(float4v*)(plane + (size_t)(ybase + (base >> 4)) * WID + tx0 + (base & 15)) = v;
            }
        }
    }
}

// 1x1 gconv GEMM: K=128 straight from NHWC.
__global__ __launch_bounds__(256, 2) void conv1x1_gemm_k(const __hip_bfloat16* __restrict__ nh,
                                                         const __hip_bfloat16* __restrict__ B1h,
                                                         float* __restrict__ out) {
    const short* nhwc = (const short*)nh;
    const short* B1 = (const short*)B1h;
    int b = blockIdx.y;
    int wave = threadIdx.x >> 6, lane = threadIdx.x & 63;
    int l31 = lane & 31, half = lane >> 5;
    int p0 = blockIdx.x * 256 + wave * 64;
    float16 acc[8];
#pragma unroll
    for (int i = 0; i < 8; i++) acc[i] = (float16)0.f;
    const short* a0p = nhwc + ((size_t)b * HW + p0 + l31) * NHWC_STRIDE + half * 8;
    const short* a1p = a0p + 32 * NHWC_STRIDE;
    const short* bp  = B1 + (size_t)l31 * 128 + half * 8;
#pragma unroll
    for (int ks = 0; ks < 8; ks++) {
        short8 a0 = *(const short8*)(a0p + ks * 16);
        short8 a1 = *(const short8*)(a1p + ks * 16);
#pragma unroll
        for (int nt = 0; nt < 4; nt++) {
            short8 bb = *(const short8*)(bp + nt * 32 * 128 + ks * 16);
            acc[nt]     = __builtin_amdgcn_mfma_f32_32x32x16_bf16(a0, bb, acc[nt], 0, 0, 0);
            acc[4 + nt] = __builtin_amdgcn_mfma_f32_32x32x16_bf16(a1, bb, acc[4 + nt], 0, 0, 0);
        }
    }
    float* outb = out + (size_t)b * PLANE_B;
#pragma unroll
    for (int g = 0; g < 2; g++)
#pragma unroll
        for (int nt = 0; nt < 4; nt++) {
            int n = nt * 32 + l31;
#pragma unroll
            for (int r4 = 0; r4 < 4; r4++) {
                int base = 8 * r4 + 4 * half;
                float4v v;
                v[0] = acc[g * 4 + nt][r4 * 4 + 0];
                v[1] = acc[g * 4 + nt][r4 * 4 + 1];
                v[2] = acc[g * 4 + nt][r4 * 4 + 2];
                v[3] = acc[g * 4 + nt][r4 * 4 + 3];
                *(float4v*)(outb + (size_t)n * HW + p0 + g * 32 + base) = v;
            }
        }
}

// ---- BN batch stats over planar fp32 ----
__global__ void zero_k(float* p, int n) {
    int i = blockIdx.x * blockDim.x + threadIdx.x;
    if (i < n) p[i] = 0.f;
}

__global__ void stats_k(const float* __restrict__ buf, float* __restrict__ stats) {
    int c = blockIdx.x;
    float s = 0.f, s2 = 0.f;
    int total = 2 * NOR * HW;
    for (int i = blockIdx.y * blockDim.x + threadIdx.x; i < total; i += gridDim.y * blockDim.x) {
        int b = i >> 19;
        int rem = i & ((1 << 19) - 1);
        float v = buf[(size_t)b * PLANE_B + (size_t)c * PLANE_C + rem];
        s += v;
        s2 += v * v;
    }
#pragma unroll
    for (int off = 32; off > 0; off >>= 1) {
        s += __shfl_down(s, off);
        s2 += __shfl_down(s2, off);
    }
    __shared__ float ls[4], ls2[4];
    int wid = threadIdx.x >> 6, lid = threadIdx.x & 63;
    if (lid == 0) { ls[wid] = s; ls2[wid] = s2; }
    __syncthreads();
    if (threadIdx.x == 0) {
        atomicAdd(&stats[c * 2], ls[0] + ls[1] + ls[2] + ls[3]);
        atomicAdd(&stats[c * 2 + 1], ls2[0] + ls2[1] + ls2[2] + ls2[3]);
    }
}

__global__ void finalize_k(const float* __restrict__ stats, const float* __restrict__ g,
                           const float* __restrict__ beta, float* __restrict__ ss) {
    int c = threadIdx.x;
    if (c >= 16) return;
    float mean = stats[c * 2] / BN_N;
    float var = stats[c * 2 + 1] / BN_N - mean * mean;
    float sc = g[c] * rsqrtf(var + 1e-5f);
    ss[c * 2] = sc;
    ss[c * 2 + 1] = beta[c] - mean * sc;
}

// ---- fused BN+ReLU + planar->NHWC(bf16, padded) repack ----
__global__ void repack_k(const float* __restrict__ planar, const float* __restrict__ ss,
                         __hip_bfloat16* __restrict__ nhwc) {
    __shared__ __hip_bfloat16 ls[128 * NHWC_STRIDE];
    int b = blockIdx.y;
    int px0 = blockIdx.x * 128;
    for (int i = threadIdx.x; i < 128 * 8; i += 256)
        ls[(i >> 3) * NHWC_STRIDE + 128 + (i & 7)] = __float2bfloat16(0.f);
    int px = threadIdx.x & 127;
    int choff = threadIdx.x >> 7;
    const float* pb = planar + (size_t)b * PLANE_B + px0 + px;
    for (int chb = 0; chb < 64; chb++) {
        int ch = chb * 2 + choff;
        int c = ch >> 3;
        float v = pb[(size_t)ch * HW];
        v = v * ss[c * 2] + ss[c * 2 + 1];
        v = v > 0.f ? v : 0.f;
        ls[px * NHWC_STRIDE + ch] = __float2bfloat16(v);
    }
    __syncthreads();
    short* outp = (short*)nhwc + ((size_t)b * HW + px0) * NHWC_STRIDE;
    const short* lsp = (const short*)ls;
    for (int i = threadIdx.x; i < 128 * 17; i += 256) {
        int p = i / 17, seg = i % 17;
        *(short8*)(outp + (size_t)p * NHWC_STRIDE + seg * 8) =
            *(const short8*)(lsp + p * NHWC_STRIDE + seg * 8);
    }
}

// ---- BN+ReLU on conv4, max over m, final 1x1 + sigmoid; dtype-flagged write ----
__global__ void final_k(const float* __restrict__ in, const float* __restrict__ ss,
                        const float* __restrict__ fw, void* __restrict__ out,
                        const int* __restrict__ flag) {
    int i = blockIdx.x * blockDim.x + threadIdx.x;
    int b = i >> 16, pix = i & 65535;
    float acc = 0.f;
#pragma unroll
    for (int co = 0; co < 16; co++) {
        float sc = ss[co * 2], sh = ss[co * 2 + 1];
        float mx = 0.f;
        const float* p = in + (size_t)b * PLANE_B + (size_t)co * PLANE_C + pix;
#pragma unroll
        for (int m = 0; m < 8; m++) mx = fmaxf(mx, p[m * HW] * sc + sh);
        acc = fmaf(fw[co], mx, acc);
    }
    float r = 1.f / (1.f + expf(-acc));
    if (*flag)
        ((__hip_bfloat16*)out)[i] = __float2bfloat16(r);
    else
        ((float*)out)[i] = r;
}

extern "C" void kernel_launch(void* const* d_in, const int* in_sizes, int n_in,
                              void* d_out, int out_size, void* d_ws, size_t ws_size,
                              hipStream_t stream) {
    float* ws = (float*)d_ws;
    float* planar = ws;                                        // 16,777,216 f
    __hip_bfloat16* nhwc = (__hip_bfloat16*)(ws + 16777216);   // 17,825,792 bf16
    __hip_bfloat16* Alift = (__hip_bfloat16*)(ws + 25690112);  // 10,485,760 bf16
    __hip_bfloat16* Bg    = (__hip_bfloat16*)(ws + 30932992);  // 409,600 bf16
    __hip_bfloat16* Blift = (__hip_bfloat16*)(ws + 31137792);  // 20,480 bf16
    __hip_bfloat16* B1    = (__hip_bfloat16*)(ws + 31148032);  // 16,384 bf16
    float* xF  = ws + 31156224;        // 393216
    float* lwF = xF + 393216;          // 2352
    float* w1F = lwF + 2352;           // 102400
    float* w2F = w1F + 102400;
    float* w3F = w2F + 102400;
    float* w4F = w3F + 102400;         // 2048
    float* fwF = w4F + 2048;           // 16
    float* gbF = fwF + 16;             // 160
    float* stats = gbF + 160;          // 32
    float* ss    = stats + 32;         // 32
    int*   flag  = (int*)(ss + 32);

    detect_k<<<1, 256, 0, stream>>>(d_in[0], flag);
    {
        float* dsts[17] = {xF, lwF, w1F, w2F, w3F, w4F, fwF,
                           gbF + 0,  gbF + 16, gbF + 32, gbF + 48, gbF + 64,
                           gbF + 80, gbF + 96, gbF + 112, gbF + 128, gbF + 144};
        for (int i = 0; i < 17; i++) {
            int n = in_sizes[i];
            cvt_k<<<(n + 255) / 256, 256, 0, stream>>>(d_in[i], dsts[i], n, flag);
        }
    }

    // ---- lift: pack B, per-batch im2col + GEMM ----
    pack_blift_k<<<(128 * 160 + 255) / 256, 256, 0, stream>>>(lwF, Blift);
    for (int b = 0; b < 2; b++) {
        im2col_lift_k<<<(HW * 160 + 255) / 256, 256, 0, stream>>>(xF + (size_t)b * 3 * HW, Alift);
        lift_gemm_k<<<256, 256, 0, stream>>>(Alift, Blift, planar + (size_t)b * PLANE_B);
    }
    zero_k<<<1, 64, 0, stream>>>(stats, 32);
    stats_k<<<dim3(16, 64), 256, 0, stream>>>(planar, stats);
    finalize_k<<<1, 64, 0, stream>>>(stats, gbF + 0, gbF + 16, ss);
    repack_k<<<dim3(512, 2), 256, 0, stream>>>(planar, ss, nhwc);

    // ---- gconv 1..3 ----
    float* wlist[3] = {w1F, w2F, w3F};
    for (int l = 0; l < 3; l++) {
        pack_bg_k<<<(25 * 128 * 128 + 255) / 256, 256, 0, stream>>>(wlist[l], Bg);
        gconv_mfma_k<<<512, 256, 0, stream>>>(nhwc, Bg, planar);
        zero_k<<<1, 64, 0, stream>>>(stats, 32);
        stats_k<<<dim3(16, 64), 256, 0, stream>>>(planar, stats);
        finalize_k<<<1, 64, 0, stream>>>(stats, gbF + 32 * (l + 1), gbF + 32 * (l + 1) + 16, ss);
        repack_k<<<dim3(512, 2), 256, 0, stream>>>(planar, ss, nhwc);
    }

    // ---- conv4 (1x1) + stats (BN/ReLU fused into final_k) ----
    pack_b1_k<<<(128 * 128 + 255) / 256, 256, 0, stream>>>(w4F, B1);
    conv1x1_gemm_k<<<dim3(256, 2), 256, 0, stream>>>(nhwc, B1, planar);
    zero_k<<<1, 64, 0, stream>>>(stats, 32);
    stats_k<<<dim3(16, 64), 256, 0, stream>>>(planar, stats);
    finalize_k<<<1, 64, 0, stream>>>(stats, gbF + 128, gbF + 144, ss);

    // ---- max-project + final 1x1 + sigmoid ----
    final_k<<<(2 * HW) / 256, 256, 0, stream>>>(planar, ss, fwF, d_out, flag);
}